// Round 1
// 554.827 us; speedup vs baseline: 1.0841x; 1.0841x over previous
//
#include <hip/hip_runtime.h>
#include <math.h>

#define F 512
#define H 16
#define C 40
#define BW 128          // nodes per bucket (dstloc fits in 7 bits)
#define BSH 7           // log2(BW)
#define NB_MAX 1024     // max buckets supported (N <= 131072)
#define CHUNK 4096      // edges per chunk
#define SEGS 8          // chunk segments for the column scan
#define SRC_BITS 17     // src < 2^17 (N = 100000)
#define SRC_MASK 0x1FFFF
#define SORT_CAP 8192   // max edges per bucket in sortb LDS (mean 4096, sd 64)

// ---------- pass A: per-chunk bucket histogram -> M[c][b], coalesced, no atomics ----------
__global__ __launch_bounds__(256) void k_hist2(const int* __restrict__ dst,
                                               int* __restrict__ M, int E, int NB) {
    __shared__ int hist[NB_MAX];
    int c = blockIdx.x, t = threadIdx.x;
    for (int b = t; b < NB; b += 256) hist[b] = 0;
    __syncthreads();
    int i0 = c * CHUNK, end = min(i0 + CHUNK, E);
    for (int i = i0 + t; i < end; i += 256)
        atomicAdd(&hist[dst[i] >> BSH], 1);
    __syncthreads();
    for (int b = t; b < NB; b += 256) M[(size_t)c * NB + b] = hist[b];
}

// ---------- column scan 1: per-(segment,bucket) sums. thread t -> (s = t/NB, b = t%NB) ----------
__global__ __launch_bounds__(256) void k_csA(const int* __restrict__ M, int* __restrict__ P,
                                             int NB, int NCH, int SEGLEN) {
    int t = blockIdx.x * 256 + threadIdx.x;
    if (t >= SEGS * NB) return;
    int s = t / NB, b = t - s * NB;
    int c0 = s * SEGLEN, c1 = min(c0 + SEGLEN, NCH);
    int sum = 0;
    for (int c = c0; c < c1; c++) sum += M[(size_t)c * NB + b];
    P[s * NB + b] = sum;
}

// ---------- merged: per-bucket segment scan (was k_csB) + bucket-base scan (was k_bscan) ----------
// one block of 1024 threads; removes one dispatch and the S[] round-trip through global.
__global__ void k_csBscan(int* __restrict__ P, int* __restrict__ brow,
                          int* __restrict__ rowptr, int NB, int N, int E) {
    __shared__ int sh[1024];
    int t = threadIdx.x;
    int run = 0;
    if (t < NB) {
        #pragma unroll
        for (int s = 0; s < SEGS; s++) {
            int v = P[s * NB + t];
            P[s * NB + t] = run;
            run += v;
        }
    }
    sh[t] = run;                       // run == bucket total (0 for t >= NB)
    __syncthreads();
    for (int off = 1; off < 1024; off <<= 1) {
        int add = (t >= off) ? sh[t - off] : 0;
        __syncthreads();
        sh[t] += add;
        __syncthreads();
    }
    if (t < NB) brow[t] = sh[t] - run; // exclusive
    if (t == 0) { brow[NB] = E; rowptr[N] = E; }
}

// ---------- column scan 3: in-place exclusive scan of M over chunks, + segment + bucket base ----------
__global__ __launch_bounds__(256) void k_csC(int* __restrict__ M, const int* __restrict__ P,
                                             const int* __restrict__ brow,
                                             int NB, int NCH, int SEGLEN) {
    int t = blockIdx.x * 256 + threadIdx.x;
    if (t >= SEGS * NB) return;
    int s = t / NB, b = t - s * NB;
    int c0 = s * SEGLEN, c1 = min(c0 + SEGLEN, NCH);
    int run = P[s * NB + b] + brow[b];
    for (int c = c0; c < c1; c++) {
        int v = M[(size_t)c * NB + b];
        M[(size_t)c * NB + b] = run;
        run += v;
    }
}

// ---------- pass C: scatter with LDS reorder -> coalesced ebuf writes ----------
// old version issued 64-way-divergent 4B stores (one transaction per lane, ~3.2M total).
// here: rank edges by bucket in LDS, then write LDS-sorted (addr,payload) pairs linearly:
// consecutive lanes hit consecutive addresses within ~5-edge bucket runs (~5x fewer transactions).
__global__ __launch_bounds__(256) void k_bscatter3(const int* __restrict__ src,
                                                   const int* __restrict__ dst,
                                                   const int* __restrict__ M,
                                                   int* __restrict__ ebuf, int E, int NB) {
    __shared__ int gbase[NB_MAX];
    __shared__ int pos[NB_MAX];
    __shared__ int cur[NB_MAX];
    __shared__ int tsum[256];
    __shared__ int paddr[CHUNK];
    __shared__ int pdata[CHUNK];     // LDS total ~45KB -> 3 blocks/CU
    int c = blockIdx.x, t = threadIdx.x;
    for (int b = t; b < NB; b += 256) {
        gbase[b] = M[(size_t)c * NB + b];
        cur[b] = 0;
    }
    __syncthreads();
    int i0 = c * CHUNK, end = min(i0 + CHUNK, E);
    for (int i = i0 + t; i < end; i += 256)
        atomicAdd(&cur[dst[i] >> BSH], 1);
    __syncthreads();
    // exclusive scan of counts over NB buckets: thread owns 4 consecutive buckets
    int b0 = t * 4;
    int v0 = (b0 + 0 < NB) ? cur[b0 + 0] : 0;
    int v1 = (b0 + 1 < NB) ? cur[b0 + 1] : 0;
    int v2 = (b0 + 2 < NB) ? cur[b0 + 2] : 0;
    int v3 = (b0 + 3 < NB) ? cur[b0 + 3] : 0;
    int loc1 = v0, loc2 = v0 + v1, loc3 = v0 + v1 + v2;
    int s = loc3 + v3;
    tsum[t] = s;
    __syncthreads();
    for (int off = 1; off < 256; off <<= 1) {
        int v = (t >= off) ? tsum[t - off] : 0;
        __syncthreads();
        tsum[t] += v;
        __syncthreads();
    }
    int excl = tsum[t] - s;
    if (b0 + 0 < NB) { int p = excl;        pos[b0 + 0] = p; cur[b0 + 0] = p; }
    if (b0 + 1 < NB) { int p = excl + loc1; pos[b0 + 1] = p; cur[b0 + 1] = p; }
    if (b0 + 2 < NB) { int p = excl + loc2; pos[b0 + 2] = p; cur[b0 + 2] = p; }
    if (b0 + 3 < NB) { int p = excl + loc3; pos[b0 + 3] = p; cur[b0 + 3] = p; }
    __syncthreads();
    for (int i = i0 + t; i < end; i += 256) {
        int d = dst[i], sv = src[i];
        int b = d >> BSH;
        int r = atomicAdd(&cur[b], 1);                 // r = pos[b] + rank-in-bucket
        paddr[r] = gbase[b] + (r - pos[b]);
        pdata[r] = ((d & (BW - 1)) << SRC_BITS) | sv;
    }
    __syncthreads();
    int n = end - i0;
    for (int i = t; i < n; i += 256)
        ebuf[paddr[i]] = pdata[i];                     // mostly-consecutive addresses
}

// ---------- per-bucket LDS counting sort: ebuf -> dst-sorted (in place), rowptr, dinv ----------
__global__ __launch_bounds__(256) void k_sortb(int* __restrict__ ebuf,
                                               const int* __restrict__ brow,
                                               int* __restrict__ rowptr,
                                               float* __restrict__ dinv, int N) {
    __shared__ int buf[SORT_CAP];        // 32 KB
    __shared__ int hist[BW];
    __shared__ int off[BW];
    __shared__ int cur[BW];
    int b = blockIdx.x;
    int beg = brow[b], end = brow[b + 1];
    int len = end - beg;
    if (len > SORT_CAP) len = SORT_CAP;  // statistically impossible (mean 4096, sd 64)
    int tid = threadIdx.x;
    if (tid < BW) hist[tid] = 0;
    for (int i = tid; i < len; i += 256) buf[i] = ebuf[beg + i];
    __syncthreads();
    for (int i = tid; i < len; i += 256)
        atomicAdd(&hist[buf[i] >> SRC_BITS], 1);
    __syncthreads();
    if (tid < BW) off[tid] = hist[tid];
    __syncthreads();
    for (int d = 1; d < BW; d <<= 1) {           // Hillis-Steele inclusive scan
        int v = (tid < BW && tid >= d) ? off[tid - d] : 0;
        __syncthreads();
        if (tid < BW) off[tid] += v;
        __syncthreads();
    }
    if (tid < BW) {
        int excl = off[tid] - hist[tid];
        int n = b * BW + tid;
        if (n < N) {
            rowptr[n] = beg + excl;
            dinv[n] = rsqrtf((float)(hist[tid] + 1));   // +1 self loop
        }
        cur[tid] = excl;
    }
    __syncthreads();
    for (int i = tid; i < len; i += 256) {
        int w = buf[i];
        int r = atomicAdd(&cur[w >> SRC_BITS], 1);
        ebuf[beg + r] = w & SRC_MASK;                   // store bare src
    }
}

// ---------- layer 1 GEMM v3: single-wave blocks, 64 nodes/wave, K-tile 64 ----------
#define KT 64
#define GST 68   // LDS row stride in words: pad 4 -> b128 banks spread evenly
__global__ __launch_bounds__(64) void k_gemm1(const float* __restrict__ x,
                                              const float* __restrict__ W1,
                                              const float* __restrict__ dinv,
                                              float* __restrict__ h0s, int N) {
    __shared__ float xs[64 * GST];   // 17408 B
    int t = threadIdx.x;             // 0..63, one node per lane
    int n0 = blockIdx.x * 64;
    float acc[H];
    #pragma unroll
    for (int j = 0; j < H; j++) acc[j] = 0.f;
    for (int kt = 0; kt < F; kt += KT) {
        __syncthreads();
        #pragma unroll
        for (int p = 0; p < 16; p++) {
            int idx = t + (p << 6);          // 0..1023
            int r = idx >> 4, c4 = idx & 15; // row 0..63, col-quad 0..15
            int v = n0 + r; if (v >= N) v = N - 1;
            float4 val = *(const float4*)(x + (size_t)v * F + kt + (c4 << 2));
            *(float4*)&xs[r * GST + (c4 << 2)] = val;
        }
        __syncthreads();
        #pragma unroll
        for (int k4 = 0; k4 < 16; k4++) {
            float4 xv = *(const float4*)&xs[t * GST + (k4 << 2)];
            const float* w = W1 + (size_t)(kt + (k4 << 2)) * H;  // wave-uniform -> s_load
            #pragma unroll
            for (int j = 0; j < H; j++) acc[j] = fmaf(xv.x, w[j], acc[j]);
            #pragma unroll
            for (int j = 0; j < H; j++) acc[j] = fmaf(xv.y, w[H + j], acc[j]);
            #pragma unroll
            for (int j = 0; j < H; j++) acc[j] = fmaf(xv.z, w[2 * H + j], acc[j]);
            #pragma unroll
            for (int j = 0; j < H; j++) acc[j] = fmaf(xv.w, w[3 * H + j], acc[j]);
        }
    }
    int v = n0 + t;
    if (v >= N) return;
    float dv = dinv[v];
    float4* o4 = (float4*)(h0s + (size_t)v * H);
    o4[0] = make_float4(acc[0] * dv, acc[1] * dv, acc[2] * dv, acc[3] * dv);
    o4[1] = make_float4(acc[4] * dv, acc[5] * dv, acc[6] * dv, acc[7] * dv);
    o4[2] = make_float4(acc[8] * dv, acc[9] * dv, acc[10] * dv, acc[11] * dv);
    o4[3] = make_float4(acc[12] * dv, acc[13] * dv, acc[14] * dv, acc[15] * dv);
}

// ---------- CSR aggregation pass 1: 4 lanes/node, float4 gathers, 8-deep MLP, relu epilogue ----------
__global__ __launch_bounds__(256) void k_agg1(const float* __restrict__ hs,
                                              const int* __restrict__ adj,
                                              const int* __restrict__ rowptr,
                                              const float* __restrict__ dinv,
                                              const float* __restrict__ b1,
                                              float* __restrict__ out, int N) {
    int t = blockIdx.x * 256 + threadIdx.x;
    int n = t >> 2, q = t & 3;
    if (n >= N) return;
    const float4* hs4 = (const float4*)hs;
    int beg = rowptr[n], end = rowptr[n + 1];
    float4 a = hs4[(size_t)n * 4 + q];   // self loop (already dinv[src]-scaled)
    float ax = a.x, ay = a.y, az = a.z, aw = a.w;
    int e = beg;
    for (; e + 7 < end; e += 8) {
        int s0 = adj[e], s1 = adj[e + 1], s2 = adj[e + 2], s3 = adj[e + 3];
        int s4 = adj[e + 4], s5 = adj[e + 5], s6 = adj[e + 6], s7 = adj[e + 7];
        float4 v0 = hs4[(size_t)s0 * 4 + q];
        float4 v1 = hs4[(size_t)s1 * 4 + q];
        float4 v2 = hs4[(size_t)s2 * 4 + q];
        float4 v3 = hs4[(size_t)s3 * 4 + q];
        float4 v4 = hs4[(size_t)s4 * 4 + q];
        float4 v5 = hs4[(size_t)s5 * 4 + q];
        float4 v6 = hs4[(size_t)s6 * 4 + q];
        float4 v7 = hs4[(size_t)s7 * 4 + q];
        ax += ((v0.x + v1.x) + (v2.x + v3.x)) + ((v4.x + v5.x) + (v6.x + v7.x));
        ay += ((v0.y + v1.y) + (v2.y + v3.y)) + ((v4.y + v5.y) + (v6.y + v7.y));
        az += ((v0.z + v1.z) + (v2.z + v3.z)) + ((v4.z + v5.z) + (v6.z + v7.z));
        aw += ((v0.w + v1.w) + (v2.w + v3.w)) + ((v4.w + v5.w) + (v6.w + v7.w));
    }
    for (; e + 3 < end; e += 4) {
        int s0 = adj[e], s1 = adj[e + 1], s2 = adj[e + 2], s3 = adj[e + 3];
        float4 v0 = hs4[(size_t)s0 * 4 + q];
        float4 v1 = hs4[(size_t)s1 * 4 + q];
        float4 v2 = hs4[(size_t)s2 * 4 + q];
        float4 v3 = hs4[(size_t)s3 * 4 + q];
        ax += (v0.x + v1.x) + (v2.x + v3.x);
        ay += (v0.y + v1.y) + (v2.y + v3.y);
        az += (v0.z + v1.z) + (v2.z + v3.z);
        aw += (v0.w + v1.w) + (v2.w + v3.w);
    }
    for (; e < end; e++) {
        int s = adj[e];
        float4 v = hs4[(size_t)s * 4 + q];
        ax += v.x; ay += v.y; az += v.z; aw += v.w;
    }
    float dv = dinv[n];
    float4 r;
    r.x = fmaxf(fmaf(dv, ax, b1[q * 4 + 0]), 0.f) * dv;
    r.y = fmaxf(fmaf(dv, ay, b1[q * 4 + 1]), 0.f) * dv;
    r.z = fmaxf(fmaf(dv, az, b1[q * 4 + 2]), 0.f) * dv;
    r.w = fmaxf(fmaf(dv, aw, b1[q * 4 + 3]), 0.f) * dv;
    ((float4*)out)[(size_t)n * 4 + q] = r;
}

// ---------- fused agg pass 2 + W2 + softmax: 4 lanes/node, 64 nodes/block ----------
// outputs staged in LDS and written as coalesced float4 (old path: stride-40 scalar stores,
// ~10 cache lines touched per store instruction over 32MB of output).
__global__ __launch_bounds__(256) void k_agg2out(const float* __restrict__ hs,
                                                 const int* __restrict__ adj,
                                                 const int* __restrict__ rowptr,
                                                 const float* __restrict__ dinv,
                                                 const float* __restrict__ W2,
                                                 const float* __restrict__ b2,
                                                 float* __restrict__ dout, int N) {
    __shared__ float sg[64 * 16];   // 4 KB aggregated layer-2 inputs
    __shared__ float w2s[H * C];    // 2.56 KB
    __shared__ float b2s[C];
    __shared__ float so[64 * 40];   // 10.24 KB output staging (reused for both outputs)
    int t = threadIdx.x;
    for (int i = t; i < H * C; i += 256) w2s[i] = W2[i];
    if (t < C) b2s[t] = b2[t];
    int nl = t >> 2, q = t & 3;
    int n0 = blockIdx.x * 64;
    int n = n0 + nl;
    bool valid = (n < N);
    int nn = valid ? n : N - 1;
    const float4* hs4 = (const float4*)hs;
    int beg = rowptr[nn], end = rowptr[nn + 1];
    float4 a = hs4[(size_t)nn * 4 + q];  // self loop
    float ax = a.x, ay = a.y, az = a.z, aw = a.w;
    int e = beg;
    for (; e + 7 < end; e += 8) {
        int s0 = adj[e], s1 = adj[e + 1], s2 = adj[e + 2], s3 = adj[e + 3];
        int s4 = adj[e + 4], s5 = adj[e + 5], s6 = adj[e + 6], s7 = adj[e + 7];
        float4 v0 = hs4[(size_t)s0 * 4 + q];
        float4 v1 = hs4[(size_t)s1 * 4 + q];
        float4 v2 = hs4[(size_t)s2 * 4 + q];
        float4 v3 = hs4[(size_t)s3 * 4 + q];
        float4 v4 = hs4[(size_t)s4 * 4 + q];
        float4 v5 = hs4[(size_t)s5 * 4 + q];
        float4 v6 = hs4[(size_t)s6 * 4 + q];
        float4 v7 = hs4[(size_t)s7 * 4 + q];
        ax += ((v0.x + v1.x) + (v2.x + v3.x)) + ((v4.x + v5.x) + (v6.x + v7.x));
        ay += ((v0.y + v1.y) + (v2.y + v3.y)) + ((v4.y + v5.y) + (v6.y + v7.y));
        az += ((v0.z + v1.z) + (v2.z + v3.z)) + ((v4.z + v5.z) + (v6.z + v7.z));
        aw += ((v0.w + v1.w) + (v2.w + v3.w)) + ((v4.w + v5.w) + (v6.w + v7.w));
    }
    for (; e + 3 < end; e += 4) {
        int s0 = adj[e], s1 = adj[e + 1], s2 = adj[e + 2], s3 = adj[e + 3];
        float4 v0 = hs4[(size_t)s0 * 4 + q];
        float4 v1 = hs4[(size_t)s1 * 4 + q];
        float4 v2 = hs4[(size_t)s2 * 4 + q];
        float4 v3 = hs4[(size_t)s3 * 4 + q];
        ax += (v0.x + v1.x) + (v2.x + v3.x);
        ay += (v0.y + v1.y) + (v2.y + v3.y);
        az += (v0.z + v1.z) + (v2.z + v3.z);
        aw += (v0.w + v1.w) + (v2.w + v3.w);
    }
    for (; e < end; e++) {
        int s = adj[e];
        float4 v = hs4[(size_t)s * 4 + q];
        ax += v.x; ay += v.y; az += v.z; aw += v.w;
    }
    float dv = dinv[nn];
    *(float4*)&sg[nl * 16 + q * 4] = make_float4(dv * ax, dv * ay, dv * az, dv * aw);
    __syncthreads();
    // phase 2: lane quad computes 10 of 40 logits for its node
    float g16[16];
    #pragma unroll
    for (int k4 = 0; k4 < 4; k4++) {
        float4 gv = *(const float4*)&sg[nl * 16 + k4 * 4];
        g16[k4 * 4] = gv.x; g16[k4 * 4 + 1] = gv.y;
        g16[k4 * 4 + 2] = gv.z; g16[k4 * 4 + 3] = gv.w;
    }
    int j0 = q * 10;
    float h2[10];
    #pragma unroll
    for (int jj = 0; jj < 10; jj++) {
        float acc = b2s[j0 + jj];
        #pragma unroll
        for (int k = 0; k < H; k++) acc = fmaf(g16[k], w2s[k * C + j0 + jj], acc);
        h2[jj] = acc;
    }
    float m = h2[0];
    #pragma unroll
    for (int jj = 1; jj < 10; jj++) m = fmaxf(m, h2[jj]);
    m = fmaxf(m, __shfl_xor(m, 1, 64));
    m = fmaxf(m, __shfl_xor(m, 2, 64));
    float ex[10], ssum = 0.f;
    #pragma unroll
    for (int jj = 0; jj < 10; jj++) { ex[jj] = __expf(h2[jj] - m); ssum += ex[jj]; }
    ssum += __shfl_xor(ssum, 1, 64);
    ssum += __shfl_xor(ssum, 2, 64);
    float inv = 1.f / ssum;
    // stage softmax rows, coalesced copy out
    int rows = min(64, N - n0);
    int tot = rows * 10;                 // float4 count for this block's rows
    #pragma unroll
    for (int jj = 0; jj < 10; jj++) so[nl * 40 + j0 + jj] = ex[jj] * inv;
    __syncthreads();
    {
        const float4* sp4 = (const float4*)so;
        float4* o4 = (float4*)(dout + (size_t)n0 * C);
        for (int i = t; i < tot; i += 256) o4[i] = sp4[i];
    }
    __syncthreads();
    // stage logits, coalesced copy out
    #pragma unroll
    for (int jj = 0; jj < 10; jj++) so[nl * 40 + j0 + jj] = h2[jj];
    __syncthreads();
    {
        const float4* sp4 = (const float4*)so;
        float4* o4 = (float4*)(dout + (size_t)N * C + (size_t)n0 * C);
        for (int i = t; i < tot; i += 256) o4[i] = sp4[i];
    }
}

extern "C" void kernel_launch(void* const* d_in, const int* in_sizes, int n_in,
                              void* d_out, int out_size, void* d_ws, size_t ws_size,
                              hipStream_t stream) {
    const float* x  = (const float*)d_in[0];
    const int*   ei = (const int*)d_in[1];
    const float* W1 = (const float*)d_in[3];
    const float* b1 = (const float*)d_in[4];
    const float* W2 = (const float*)d_in[5];
    const float* b2 = (const float*)d_in[6];
    float* out = (float*)d_out;

    int N = in_sizes[0] / F;       // 100000
    int E = in_sizes[1] / 2;       // 3200000
    const int* src = ei;
    const int* dst = ei + E;
    int NB  = (N + BW - 1) / BW;            // 782 (<= NB_MAX)
    int NCH = (E + CHUNK - 1) / CHUNK;      // 782
    int SEGLEN = (NCH + SEGS - 1) / SEGS;   // 98

    // workspace layout
    float* ws = (float*)d_ws;
    size_t o = 0;
    int* M      = (int*)(ws + o); o += (size_t)NCH * NB;
    int* P      = (int*)(ws + o); o += (size_t)SEGS * NB_MAX;
    int* brow   = (int*)(ws + o); o += (size_t)NB_MAX + 4;
    int* rowptr = (int*)(ws + o); o += (size_t)N + 4;
    int* ebuf   = (int*)(ws + o); o += (size_t)E;
    float* dinv = ws + o;         o += (size_t)N;
    float* h0s  = ws + o;         o += (size_t)N * H;
    float* h1s  = ws + o;         o += (size_t)N * H;

    int ng  = (N + 63) / 64;                     // 1563
    int ncs = (SEGS * NB + 255) / 256;           // 25

    k_hist2    <<<NCH, 256, 0, stream>>>(dst, M, E, NB);
    k_csA      <<<ncs, 256, 0, stream>>>(M, P, NB, NCH, SEGLEN);
    k_csBscan  <<<1, 1024, 0, stream>>>(P, brow, rowptr, NB, N, E);
    k_csC      <<<ncs, 256, 0, stream>>>(M, P, brow, NB, NCH, SEGLEN);
    k_bscatter3<<<NCH, 256, 0, stream>>>(src, dst, M, ebuf, E, NB);
    k_sortb    <<<NB, 256, 0, stream>>>(ebuf, brow, rowptr, dinv, N);
    k_gemm1    <<<ng, 64, 0, stream>>>(x, W1, dinv, h0s, N);
    k_agg1     <<<(N * 4 + 255) / 256, 256, 0, stream>>>(h0s, ebuf, rowptr, dinv, b1, h1s, N);
    k_agg2out  <<<ng, 256, 0, stream>>>(h1s, ebuf, rowptr, dinv, W2, b2, out, N);
}

// Round 2
// 541.054 us; speedup vs baseline: 1.1117x; 1.0255x over previous
//
#include <hip/hip_runtime.h>
#include <math.h>

#define F 512
#define H 16
#define C 40
#define BW 128          // nodes per bucket (dstloc fits in 7 bits)
#define BSH 7           // log2(BW)
#define NB_MAX 1024     // max buckets supported (N <= 131072)
#define CHUNK 4096      // edges per chunk
#define EPT 16          // edges per thread (CHUNK / 256)
#define SRC_BITS 17     // src < 2^17 (N = 100000)
#define SRC_MASK 0x1FFFF
#define SORT_CAP 8192   // fixed per-bucket capacity (mean 4096, sd 64 -> +64 sd)

// ---------- fused scatter: reg-staged edges, LDS hist, global atomic base reserve,
// ---------- LDS rank reorder, coalesced ebuf writes. Replaces hist2+csA+csBscan+csC+bscatter3.
// bucket b owns ebuf[b*SORT_CAP ...]; within-bucket order is nondeterministic, which is fine
// because sortb re-sorts the bucket and float-sum tolerance already covers reordering.
__global__ __launch_bounds__(256) void k_scatfuse(const int* __restrict__ src,
                                                  const int* __restrict__ dst,
                                                  int* __restrict__ gcnt,
                                                  int* __restrict__ ebuf, int E, int NB) {
    __shared__ int hist[NB_MAX];
    __shared__ int base2[NB_MAX];   // (b*SORT_CAP + global_base) - block_pos
    __shared__ int cur[NB_MAX];
    __shared__ int tsum[256];
    __shared__ int paddr[CHUNK];
    __shared__ int pdata[CHUNK];    // LDS ~45KB -> 3 blocks/CU
    int c = blockIdx.x, t = threadIdx.x;
    int i0 = c * CHUNK;
    int nval = min(CHUNK, E - i0);
    for (int b = t; b < NB; b += 256) hist[b] = 0;
    // stage this thread's edges in registers (single pass over dst/src)
    int dreg[EPT], sreg[EPT];
    #pragma unroll
    for (int j = 0; j < EPT; j++) {
        int i = t + j * 256;
        if (i < nval) { dreg[j] = dst[i0 + i]; sreg[j] = src[i0 + i]; }
        else dreg[j] = -1;
    }
    __syncthreads();
    #pragma unroll
    for (int j = 0; j < EPT; j++)
        if (dreg[j] >= 0) atomicAdd(&hist[dreg[j] >> BSH], 1);
    __syncthreads();
    // block-level exclusive scan over buckets: thread owns 4 consecutive buckets
    int b0 = t * 4;
    int v0 = (b0 + 0 < NB) ? hist[b0 + 0] : 0;
    int v1 = (b0 + 1 < NB) ? hist[b0 + 1] : 0;
    int v2 = (b0 + 2 < NB) ? hist[b0 + 2] : 0;
    int v3 = (b0 + 3 < NB) ? hist[b0 + 3] : 0;
    int loc1 = v0, loc2 = v0 + v1, loc3 = v0 + v1 + v2;
    int s = loc3 + v3;
    tsum[t] = s;
    __syncthreads();
    for (int off = 1; off < 256; off <<= 1) {
        int v = (t >= off) ? tsum[t - off] : 0;
        __syncthreads();
        tsum[t] += v;
        __syncthreads();
    }
    int excl = tsum[t] - s;
    // reserve global bucket ranges; fold base and block-pos into one addend
    if (b0 + 0 < NB) { int p = excl;        cur[b0+0] = p; int g = v0 ? atomicAdd(&gcnt[b0+0], v0) : 0; base2[b0+0] = (b0+0)*SORT_CAP + g - p; }
    if (b0 + 1 < NB) { int p = excl + loc1; cur[b0+1] = p; int g = v1 ? atomicAdd(&gcnt[b0+1], v1) : 0; base2[b0+1] = (b0+1)*SORT_CAP + g - p; }
    if (b0 + 2 < NB) { int p = excl + loc2; cur[b0+2] = p; int g = v2 ? atomicAdd(&gcnt[b0+2], v2) : 0; base2[b0+2] = (b0+2)*SORT_CAP + g - p; }
    if (b0 + 3 < NB) { int p = excl + loc3; cur[b0+3] = p; int g = v3 ? atomicAdd(&gcnt[b0+3], v3) : 0; base2[b0+3] = (b0+3)*SORT_CAP + g - p; }
    __syncthreads();
    #pragma unroll
    for (int j = 0; j < EPT; j++) {
        int d = dreg[j];
        if (d < 0) continue;
        int b = d >> BSH;
        int r = atomicAdd(&cur[b], 1);      // compact block-local rank
        paddr[r] = base2[b] + r;
        pdata[r] = ((d & (BW - 1)) << SRC_BITS) | sreg[j];
    }
    __syncthreads();
    for (int i = t; i < nval; i += 256)
        ebuf[paddr[i]] = pdata[i];          // mostly-consecutive addresses
}

// ---------- per-bucket LDS counting sort: ebuf -> dst-sorted (in place), rowbeg/rowend, dinv ----------
__global__ __launch_bounds__(256) void k_sortb(int* __restrict__ ebuf,
                                               const int* __restrict__ gcnt,
                                               int* __restrict__ rowbeg,
                                               int* __restrict__ rowend,
                                               float* __restrict__ dinv, int N) {
    __shared__ int buf[SORT_CAP];        // 32 KB
    __shared__ int hist[BW];
    __shared__ int off[BW];
    __shared__ int cur[BW];
    int b = blockIdx.x;
    int beg = b * SORT_CAP;
    int len = gcnt[b];
    if (len > SORT_CAP) len = SORT_CAP;  // statistically impossible (mean 4096, sd 64)
    int tid = threadIdx.x;
    if (tid < BW) hist[tid] = 0;
    for (int i = tid; i < len; i += 256) buf[i] = ebuf[beg + i];
    __syncthreads();
    for (int i = tid; i < len; i += 256)
        atomicAdd(&hist[buf[i] >> SRC_BITS], 1);
    __syncthreads();
    if (tid < BW) off[tid] = hist[tid];
    __syncthreads();
    for (int d = 1; d < BW; d <<= 1) {           // Hillis-Steele inclusive scan
        int v = (tid < BW && tid >= d) ? off[tid - d] : 0;
        __syncthreads();
        if (tid < BW) off[tid] += v;
        __syncthreads();
    }
    if (tid < BW) {
        int excl = off[tid] - hist[tid];
        int n = b * BW + tid;
        if (n < N) {
            rowbeg[n] = beg + excl;
            rowend[n] = beg + off[tid];
            dinv[n] = rsqrtf((float)(hist[tid] + 1));   // +1 self loop
        }
        cur[tid] = excl;
    }
    __syncthreads();
    for (int i = tid; i < len; i += 256) {
        int w = buf[i];
        int r = atomicAdd(&cur[w >> SRC_BITS], 1);
        ebuf[beg + r] = w & SRC_MASK;                   // store bare src
    }
}

// ---------- layer 1 GEMM v3: single-wave blocks, 64 nodes/wave, K-tile 64 ----------
#define KT 64
#define GST 68   // LDS row stride in words: pad 4 -> b128 banks spread evenly
__global__ __launch_bounds__(64) void k_gemm1(const float* __restrict__ x,
                                              const float* __restrict__ W1,
                                              const float* __restrict__ dinv,
                                              float* __restrict__ h0s, int N) {
    __shared__ float xs[64 * GST];   // 17408 B
    int t = threadIdx.x;             // 0..63, one node per lane
    int n0 = blockIdx.x * 64;
    float acc[H];
    #pragma unroll
    for (int j = 0; j < H; j++) acc[j] = 0.f;
    for (int kt = 0; kt < F; kt += KT) {
        __syncthreads();
        #pragma unroll
        for (int p = 0; p < 16; p++) {
            int idx = t + (p << 6);          // 0..1023
            int r = idx >> 4, c4 = idx & 15; // row 0..63, col-quad 0..15
            int v = n0 + r; if (v >= N) v = N - 1;
            float4 val = *(const float4*)(x + (size_t)v * F + kt + (c4 << 2));
            *(float4*)&xs[r * GST + (c4 << 2)] = val;
        }
        __syncthreads();
        #pragma unroll
        for (int k4 = 0; k4 < 16; k4++) {
            float4 xv = *(const float4*)&xs[t * GST + (k4 << 2)];
            const float* w = W1 + (size_t)(kt + (k4 << 2)) * H;  // wave-uniform -> s_load
            #pragma unroll
            for (int j = 0; j < H; j++) acc[j] = fmaf(xv.x, w[j], acc[j]);
            #pragma unroll
            for (int j = 0; j < H; j++) acc[j] = fmaf(xv.y, w[H + j], acc[j]);
            #pragma unroll
            for (int j = 0; j < H; j++) acc[j] = fmaf(xv.z, w[2 * H + j], acc[j]);
            #pragma unroll
            for (int j = 0; j < H; j++) acc[j] = fmaf(xv.w, w[3 * H + j], acc[j]);
        }
    }
    int v = n0 + t;
    if (v >= N) return;
    float dv = dinv[v];
    float4* o4 = (float4*)(h0s + (size_t)v * H);
    o4[0] = make_float4(acc[0] * dv, acc[1] * dv, acc[2] * dv, acc[3] * dv);
    o4[1] = make_float4(acc[4] * dv, acc[5] * dv, acc[6] * dv, acc[7] * dv);
    o4[2] = make_float4(acc[8] * dv, acc[9] * dv, acc[10] * dv, acc[11] * dv);
    o4[3] = make_float4(acc[12] * dv, acc[13] * dv, acc[14] * dv, acc[15] * dv);
}

// ---------- CSR aggregation pass 1: 4 lanes/node, float4 gathers, 8-deep MLP, relu epilogue ----------
__global__ __launch_bounds__(256) void k_agg1(const float* __restrict__ hs,
                                              const int* __restrict__ adj,
                                              const int* __restrict__ rowbeg,
                                              const int* __restrict__ rowend,
                                              const float* __restrict__ dinv,
                                              const float* __restrict__ b1,
                                              float* __restrict__ out, int N) {
    int t = blockIdx.x * 256 + threadIdx.x;
    int n = t >> 2, q = t & 3;
    if (n >= N) return;
    const float4* hs4 = (const float4*)hs;
    int beg = rowbeg[n], end = rowend[n];
    float4 a = hs4[(size_t)n * 4 + q];   // self loop (already dinv[src]-scaled)
    float ax = a.x, ay = a.y, az = a.z, aw = a.w;
    int e = beg;
    for (; e + 7 < end; e += 8) {
        int s0 = adj[e], s1 = adj[e + 1], s2 = adj[e + 2], s3 = adj[e + 3];
        int s4 = adj[e + 4], s5 = adj[e + 5], s6 = adj[e + 6], s7 = adj[e + 7];
        float4 v0 = hs4[(size_t)s0 * 4 + q];
        float4 v1 = hs4[(size_t)s1 * 4 + q];
        float4 v2 = hs4[(size_t)s2 * 4 + q];
        float4 v3 = hs4[(size_t)s3 * 4 + q];
        float4 v4 = hs4[(size_t)s4 * 4 + q];
        float4 v5 = hs4[(size_t)s5 * 4 + q];
        float4 v6 = hs4[(size_t)s6 * 4 + q];
        float4 v7 = hs4[(size_t)s7 * 4 + q];
        ax += ((v0.x + v1.x) + (v2.x + v3.x)) + ((v4.x + v5.x) + (v6.x + v7.x));
        ay += ((v0.y + v1.y) + (v2.y + v3.y)) + ((v4.y + v5.y) + (v6.y + v7.y));
        az += ((v0.z + v1.z) + (v2.z + v3.z)) + ((v4.z + v5.z) + (v6.z + v7.z));
        aw += ((v0.w + v1.w) + (v2.w + v3.w)) + ((v4.w + v5.w) + (v6.w + v7.w));
    }
    for (; e + 3 < end; e += 4) {
        int s0 = adj[e], s1 = adj[e + 1], s2 = adj[e + 2], s3 = adj[e + 3];
        float4 v0 = hs4[(size_t)s0 * 4 + q];
        float4 v1 = hs4[(size_t)s1 * 4 + q];
        float4 v2 = hs4[(size_t)s2 * 4 + q];
        float4 v3 = hs4[(size_t)s3 * 4 + q];
        ax += (v0.x + v1.x) + (v2.x + v3.x);
        ay += (v0.y + v1.y) + (v2.y + v3.y);
        az += (v0.z + v1.z) + (v2.z + v3.z);
        aw += (v0.w + v1.w) + (v2.w + v3.w);
    }
    for (; e < end; e++) {
        int s = adj[e];
        float4 v = hs4[(size_t)s * 4 + q];
        ax += v.x; ay += v.y; az += v.z; aw += v.w;
    }
    float dv = dinv[n];
    float4 r;
    r.x = fmaxf(fmaf(dv, ax, b1[q * 4 + 0]), 0.f) * dv;
    r.y = fmaxf(fmaf(dv, ay, b1[q * 4 + 1]), 0.f) * dv;
    r.z = fmaxf(fmaf(dv, az, b1[q * 4 + 2]), 0.f) * dv;
    r.w = fmaxf(fmaf(dv, aw, b1[q * 4 + 3]), 0.f) * dv;
    ((float4*)out)[(size_t)n * 4 + q] = r;
}

// ---------- fused agg pass 2 + W2 + softmax: 4 lanes/node, 64 nodes/block, LDS-staged stores ----------
__global__ __launch_bounds__(256) void k_agg2out(const float* __restrict__ hs,
                                                 const int* __restrict__ adj,
                                                 const int* __restrict__ rowbeg,
                                                 const int* __restrict__ rowend,
                                                 const float* __restrict__ dinv,
                                                 const float* __restrict__ W2,
                                                 const float* __restrict__ b2,
                                                 float* __restrict__ dout, int N) {
    __shared__ float sg[64 * 16];   // 4 KB aggregated layer-2 inputs
    __shared__ float w2s[H * C];    // 2.56 KB
    __shared__ float b2s[C];
    __shared__ float so[64 * 40];   // 10.24 KB output staging (reused for both outputs)
    int t = threadIdx.x;
    for (int i = t; i < H * C; i += 256) w2s[i] = W2[i];
    if (t < C) b2s[t] = b2[t];
    int nl = t >> 2, q = t & 3;
    int n0 = blockIdx.x * 64;
    int n = n0 + nl;
    bool valid = (n < N);
    int nn = valid ? n : N - 1;
    const float4* hs4 = (const float4*)hs;
    int beg = rowbeg[nn], end = rowend[nn];
    float4 a = hs4[(size_t)nn * 4 + q];  // self loop
    float ax = a.x, ay = a.y, az = a.z, aw = a.w;
    int e = beg;
    for (; e + 7 < end; e += 8) {
        int s0 = adj[e], s1 = adj[e + 1], s2 = adj[e + 2], s3 = adj[e + 3];
        int s4 = adj[e + 4], s5 = adj[e + 5], s6 = adj[e + 6], s7 = adj[e + 7];
        float4 v0 = hs4[(size_t)s0 * 4 + q];
        float4 v1 = hs4[(size_t)s1 * 4 + q];
        float4 v2 = hs4[(size_t)s2 * 4 + q];
        float4 v3 = hs4[(size_t)s3 * 4 + q];
        float4 v4 = hs4[(size_t)s4 * 4 + q];
        float4 v5 = hs4[(size_t)s5 * 4 + q];
        float4 v6 = hs4[(size_t)s6 * 4 + q];
        float4 v7 = hs4[(size_t)s7 * 4 + q];
        ax += ((v0.x + v1.x) + (v2.x + v3.x)) + ((v4.x + v5.x) + (v6.x + v7.x));
        ay += ((v0.y + v1.y) + (v2.y + v3.y)) + ((v4.y + v5.y) + (v6.y + v7.y));
        az += ((v0.z + v1.z) + (v2.z + v3.z)) + ((v4.z + v5.z) + (v6.z + v7.z));
        aw += ((v0.w + v1.w) + (v2.w + v3.w)) + ((v4.w + v5.w) + (v6.w + v7.w));
    }
    for (; e + 3 < end; e += 4) {
        int s0 = adj[e], s1 = adj[e + 1], s2 = adj[e + 2], s3 = adj[e + 3];
        float4 v0 = hs4[(size_t)s0 * 4 + q];
        float4 v1 = hs4[(size_t)s1 * 4 + q];
        float4 v2 = hs4[(size_t)s2 * 4 + q];
        float4 v3 = hs4[(size_t)s3 * 4 + q];
        ax += (v0.x + v1.x) + (v2.x + v3.x);
        ay += (v0.y + v1.y) + (v2.y + v3.y);
        az += (v0.z + v1.z) + (v2.z + v3.z);
        aw += (v0.w + v1.w) + (v2.w + v3.w);
    }
    for (; e < end; e++) {
        int s = adj[e];
        float4 v = hs4[(size_t)s * 4 + q];
        ax += v.x; ay += v.y; az += v.z; aw += v.w;
    }
    float dv = dinv[nn];
    *(float4*)&sg[nl * 16 + q * 4] = make_float4(dv * ax, dv * ay, dv * az, dv * aw);
    __syncthreads();
    // phase 2: lane quad computes 10 of 40 logits for its node
    float g16[16];
    #pragma unroll
    for (int k4 = 0; k4 < 4; k4++) {
        float4 gv = *(const float4*)&sg[nl * 16 + k4 * 4];
        g16[k4 * 4] = gv.x; g16[k4 * 4 + 1] = gv.y;
        g16[k4 * 4 + 2] = gv.z; g16[k4 * 4 + 3] = gv.w;
    }
    int j0 = q * 10;
    float h2[10];
    #pragma unroll
    for (int jj = 0; jj < 10; jj++) {
        float acc = b2s[j0 + jj];
        #pragma unroll
        for (int k = 0; k < H; k++) acc = fmaf(g16[k], w2s[k * C + j0 + jj], acc);
        h2[jj] = acc;
    }
    float m = h2[0];
    #pragma unroll
    for (int jj = 1; jj < 10; jj++) m = fmaxf(m, h2[jj]);
    m = fmaxf(m, __shfl_xor(m, 1, 64));
    m = fmaxf(m, __shfl_xor(m, 2, 64));
    float ex[10], ssum = 0.f;
    #pragma unroll
    for (int jj = 0; jj < 10; jj++) { ex[jj] = __expf(h2[jj] - m); ssum += ex[jj]; }
    ssum += __shfl_xor(ssum, 1, 64);
    ssum += __shfl_xor(ssum, 2, 64);
    float inv = 1.f / ssum;
    // stage softmax rows, coalesced copy out
    int rows = min(64, N - n0);
    int tot = rows * 10;                 // float4 count for this block's rows
    #pragma unroll
    for (int jj = 0; jj < 10; jj++) so[nl * 40 + j0 + jj] = ex[jj] * inv;
    __syncthreads();
    {
        const float4* sp4 = (const float4*)so;
        float4* o4 = (float4*)(dout + (size_t)n0 * C);
        for (int i = t; i < tot; i += 256) o4[i] = sp4[i];
    }
    __syncthreads();
    // stage logits, coalesced copy out
    #pragma unroll
    for (int jj = 0; jj < 10; jj++) so[nl * 40 + j0 + jj] = h2[jj];
    __syncthreads();
    {
        const float4* sp4 = (const float4*)so;
        float4* o4 = (float4*)(dout + (size_t)N * C + (size_t)n0 * C);
        for (int i = t; i < tot; i += 256) o4[i] = sp4[i];
    }
}

extern "C" void kernel_launch(void* const* d_in, const int* in_sizes, int n_in,
                              void* d_out, int out_size, void* d_ws, size_t ws_size,
                              hipStream_t stream) {
    const float* x  = (const float*)d_in[0];
    const int*   ei = (const int*)d_in[1];
    const float* W1 = (const float*)d_in[3];
    const float* b1 = (const float*)d_in[4];
    const float* W2 = (const float*)d_in[5];
    const float* b2 = (const float*)d_in[6];
    float* out = (float*)d_out;

    int N = in_sizes[0] / F;       // 100000
    int E = in_sizes[1] / 2;       // 3200000
    const int* src = ei;
    const int* dst = ei + E;
    int NB  = (N + BW - 1) / BW;            // 782 (<= NB_MAX)
    int NCH = (E + CHUNK - 1) / CHUNK;      // 782

    // workspace layout
    float* ws = (float*)d_ws;
    size_t o = 0;
    int* gcnt   = (int*)(ws + o); o += (size_t)NB_MAX;
    int* rowbeg = (int*)(ws + o); o += (size_t)N + 4;
    int* rowend = (int*)(ws + o); o += (size_t)N + 4;
    int* ebuf   = (int*)(ws + o); o += (size_t)NB * SORT_CAP + CHUNK;  // strided buckets + slack
    float* dinv = ws + o;         o += (size_t)N;
    float* h0s  = ws + o;         o += (size_t)N * H;
    float* h1s  = ws + o;         o += (size_t)N * H;

    int ng = (N + 63) / 64;                      // 1563

    hipMemsetAsync(gcnt, 0, (size_t)NB * sizeof(int), stream);
    k_scatfuse<<<NCH, 256, 0, stream>>>(src, dst, gcnt, ebuf, E, NB);
    k_sortb   <<<NB, 256, 0, stream>>>(ebuf, gcnt, rowbeg, rowend, dinv, N);
    k_gemm1   <<<ng, 64, 0, stream>>>(x, W1, dinv, h0s, N);
    k_agg1    <<<(N * 4 + 255) / 256, 256, 0, stream>>>(h0s, ebuf, rowbeg, rowend, dinv, b1, h1s, N);
    k_agg2out <<<ng, 256, 0, stream>>>(h1s, ebuf, rowbeg, rowend, dinv, W2, b2, out, N);
}

// Round 3
// 530.288 us; speedup vs baseline: 1.1343x; 1.0203x over previous
//
#include <hip/hip_runtime.h>
#include <math.h>

#define F 512
#define H 16
#define C 40
#define BW 128          // nodes per bucket (dstloc fits in 7 bits)
#define BSH 7           // log2(BW)
#define NB_MAX 1024     // max buckets supported (N <= 131072)
#define CHUNK 4096      // edges per chunk
#define EPT 16          // edges per thread (CHUNK / 256)
#define SRC_BITS 17     // src < 2^17 (N = 100000)
#define SRC_MASK 0x1FFFF
#define SORT_CAP 8192   // fixed per-bucket capacity (mean 4096, sd 64 -> +64 sd)

// ---------- fused scatter: int4-staged edges, LDS hist, global atomic base reserve,
// ---------- LDS rank reorder, coalesced ebuf writes.
__global__ __launch_bounds__(256) void k_scatfuse(const int* __restrict__ src,
                                                  const int* __restrict__ dst,
                                                  int* __restrict__ gcnt,
                                                  int* __restrict__ ebuf, int E, int NB) {
    __shared__ int hist[NB_MAX];
    __shared__ int base2[NB_MAX];   // (b*SORT_CAP + global_base) - block_pos
    __shared__ int cur[NB_MAX];
    __shared__ int tsum[256];
    __shared__ int paddr[CHUNK];
    __shared__ int pdata[CHUNK];    // LDS ~45KB -> 3 blocks/CU
    int c = blockIdx.x, t = threadIdx.x;
    int i0 = c * CHUNK;
    int nval = min(CHUNK, E - i0);
    for (int b = t; b < NB; b += 256) hist[b] = 0;
    // stage this thread's edges in registers via int4 loads (CHUNK is 16B-aligned)
    const int4* s4 = (const int4*)(src + i0);
    const int4* d4 = (const int4*)(dst + i0);
    int dreg[EPT], sreg[EPT];
    #pragma unroll
    for (int j = 0; j < EPT / 4; j++) {
        int i4 = t + j * 256;
        int base = i4 * 4;
        if (base + 3 < nval) {
            int4 dv = d4[i4], sv = s4[i4];
            dreg[j*4+0] = dv.x; dreg[j*4+1] = dv.y; dreg[j*4+2] = dv.z; dreg[j*4+3] = dv.w;
            sreg[j*4+0] = sv.x; sreg[j*4+1] = sv.y; sreg[j*4+2] = sv.z; sreg[j*4+3] = sv.w;
        } else {
            #pragma unroll
            for (int k = 0; k < 4; k++) {
                int idx = base + k;
                if (idx < nval) { dreg[j*4+k] = dst[i0 + idx]; sreg[j*4+k] = src[i0 + idx]; }
                else dreg[j*4+k] = -1;
            }
        }
    }
    __syncthreads();
    #pragma unroll
    for (int j = 0; j < EPT; j++)
        if (dreg[j] >= 0) atomicAdd(&hist[dreg[j] >> BSH], 1);
    __syncthreads();
    // block-level exclusive scan over buckets: thread owns 4 consecutive buckets
    int b0 = t * 4;
    int v0 = (b0 + 0 < NB) ? hist[b0 + 0] : 0;
    int v1 = (b0 + 1 < NB) ? hist[b0 + 1] : 0;
    int v2 = (b0 + 2 < NB) ? hist[b0 + 2] : 0;
    int v3 = (b0 + 3 < NB) ? hist[b0 + 3] : 0;
    int loc1 = v0, loc2 = v0 + v1, loc3 = v0 + v1 + v2;
    int s = loc3 + v3;
    tsum[t] = s;
    __syncthreads();
    for (int off = 1; off < 256; off <<= 1) {
        int v = (t >= off) ? tsum[t - off] : 0;
        __syncthreads();
        tsum[t] += v;
        __syncthreads();
    }
    int excl = tsum[t] - s;
    // reserve global bucket ranges; fold base and block-pos into one addend
    if (b0 + 0 < NB) { int p = excl;        cur[b0+0] = p; int g = v0 ? atomicAdd(&gcnt[b0+0], v0) : 0; base2[b0+0] = (b0+0)*SORT_CAP + g - p; }
    if (b0 + 1 < NB) { int p = excl + loc1; cur[b0+1] = p; int g = v1 ? atomicAdd(&gcnt[b0+1], v1) : 0; base2[b0+1] = (b0+1)*SORT_CAP + g - p; }
    if (b0 + 2 < NB) { int p = excl + loc2; cur[b0+2] = p; int g = v2 ? atomicAdd(&gcnt[b0+2], v2) : 0; base2[b0+2] = (b0+2)*SORT_CAP + g - p; }
    if (b0 + 3 < NB) { int p = excl + loc3; cur[b0+3] = p; int g = v3 ? atomicAdd(&gcnt[b0+3], v3) : 0; base2[b0+3] = (b0+3)*SORT_CAP + g - p; }
    __syncthreads();
    #pragma unroll
    for (int j = 0; j < EPT; j++) {
        int d = dreg[j];
        if (d < 0) continue;
        int b = d >> BSH;
        int r = atomicAdd(&cur[b], 1);      // compact block-local rank
        paddr[r] = base2[b] + r;
        pdata[r] = ((d & (BW - 1)) << SRC_BITS) | sreg[j];
    }
    __syncthreads();
    for (int i = t; i < nval; i += 256)
        ebuf[paddr[i]] = pdata[i];          // mostly-consecutive addresses
}

// ---------- per-bucket counting sort v2: int4 reads (2 passes, 2nd L2-hot),
// ---------- LDS permute, coalesced int4 writeback. rowbe packed int2.
__global__ __launch_bounds__(256) void k_sortb(int* __restrict__ ebuf,
                                               const int* __restrict__ gcnt,
                                               int2* __restrict__ rowbe,
                                               float* __restrict__ dinv, int N) {
    __shared__ int out[SORT_CAP];        // 32 KB permute dest
    __shared__ int hist[BW];
    __shared__ int off[BW];
    __shared__ int cur[BW];
    int b = blockIdx.x;
    int beg = b * SORT_CAP;
    int len = gcnt[b];
    if (len > SORT_CAP) len = SORT_CAP;  // statistically impossible (mean 4096, sd 64)
    int tid = threadIdx.x;
    if (tid < BW) hist[tid] = 0;
    __syncthreads();
    int len4 = len >> 2;
    const int4* e4 = (const int4*)(ebuf + beg);   // 32KB-aligned
    for (int i = tid; i < len4; i += 256) {
        int4 w = e4[i];
        atomicAdd(&hist[w.x >> SRC_BITS], 1);
        atomicAdd(&hist[w.y >> SRC_BITS], 1);
        atomicAdd(&hist[w.z >> SRC_BITS], 1);
        atomicAdd(&hist[w.w >> SRC_BITS], 1);
    }
    for (int i = (len4 << 2) + tid; i < len; i += 256)
        atomicAdd(&hist[ebuf[beg + i] >> SRC_BITS], 1);
    __syncthreads();
    if (tid < BW) off[tid] = hist[tid];
    __syncthreads();
    for (int d = 1; d < BW; d <<= 1) {           // Hillis-Steele inclusive scan
        int v = (tid < BW && tid >= d) ? off[tid - d] : 0;
        __syncthreads();
        if (tid < BW) off[tid] += v;
        __syncthreads();
    }
    if (tid < BW) {
        int excl = off[tid] - hist[tid];
        int n = b * BW + tid;
        if (n < N) {
            rowbe[n] = make_int2(beg + excl, beg + off[tid]);
            dinv[n] = rsqrtf((float)(hist[tid] + 1));   // +1 self loop
        }
        cur[tid] = excl;
    }
    __syncthreads();
    // pass 2: re-read (L2-hot), rank, permute into LDS
    for (int i = tid; i < len4; i += 256) {
        int4 w = e4[i];
        int r0 = atomicAdd(&cur[w.x >> SRC_BITS], 1);
        int r1 = atomicAdd(&cur[w.y >> SRC_BITS], 1);
        int r2 = atomicAdd(&cur[w.z >> SRC_BITS], 1);
        int r3 = atomicAdd(&cur[w.w >> SRC_BITS], 1);
        out[r0] = w.x & SRC_MASK;
        out[r1] = w.y & SRC_MASK;
        out[r2] = w.z & SRC_MASK;
        out[r3] = w.w & SRC_MASK;
    }
    for (int i = (len4 << 2) + tid; i < len; i += 256) {
        int w = ebuf[beg + i];
        int r = atomicAdd(&cur[w >> SRC_BITS], 1);
        out[r] = w & SRC_MASK;
    }
    __syncthreads();
    // coalesced int4 writeback (rounded up; slack stays inside this bucket's capacity)
    int n4 = (len + 3) >> 2;
    int4* o4 = (int4*)(ebuf + beg);
    const int4* p4 = (const int4*)out;
    for (int i = tid; i < n4; i += 256) o4[i] = p4[i];
}

// ---------- layer 1 GEMM v3: single-wave blocks, 64 nodes/wave, K-tile 64 ----------
#define KT 64
#define GST 68   // LDS row stride in words: pad 4 -> b128 banks spread evenly
__global__ __launch_bounds__(64) void k_gemm1(const float* __restrict__ x,
                                              const float* __restrict__ W1,
                                              const float* __restrict__ dinv,
                                              float* __restrict__ h0s, int N) {
    __shared__ float xs[64 * GST];   // 17408 B
    int t = threadIdx.x;             // 0..63, one node per lane
    int n0 = blockIdx.x * 64;
    float acc[H];
    #pragma unroll
    for (int j = 0; j < H; j++) acc[j] = 0.f;
    for (int kt = 0; kt < F; kt += KT) {
        __syncthreads();
        #pragma unroll
        for (int p = 0; p < 16; p++) {
            int idx = t + (p << 6);          // 0..1023
            int r = idx >> 4, c4 = idx & 15; // row 0..63, col-quad 0..15
            int v = n0 + r; if (v >= N) v = N - 1;
            float4 val = *(const float4*)(x + (size_t)v * F + kt + (c4 << 2));
            *(float4*)&xs[r * GST + (c4 << 2)] = val;
        }
        __syncthreads();
        #pragma unroll
        for (int k4 = 0; k4 < 16; k4++) {
            float4 xv = *(const float4*)&xs[t * GST + (k4 << 2)];
            const float* w = W1 + (size_t)(kt + (k4 << 2)) * H;  // wave-uniform -> s_load
            #pragma unroll
            for (int j = 0; j < H; j++) acc[j] = fmaf(xv.x, w[j], acc[j]);
            #pragma unroll
            for (int j = 0; j < H; j++) acc[j] = fmaf(xv.y, w[H + j], acc[j]);
            #pragma unroll
            for (int j = 0; j < H; j++) acc[j] = fmaf(xv.z, w[2 * H + j], acc[j]);
            #pragma unroll
            for (int j = 0; j < H; j++) acc[j] = fmaf(xv.w, w[3 * H + j], acc[j]);
        }
    }
    int v = n0 + t;
    if (v >= N) return;
    float dv = dinv[v];
    float4* o4 = (float4*)(h0s + (size_t)v * H);
    o4[0] = make_float4(acc[0] * dv, acc[1] * dv, acc[2] * dv, acc[3] * dv);
    o4[1] = make_float4(acc[4] * dv, acc[5] * dv, acc[6] * dv, acc[7] * dv);
    o4[2] = make_float4(acc[8] * dv, acc[9] * dv, acc[10] * dv, acc[11] * dv);
    o4[3] = make_float4(acc[12] * dv, acc[13] * dv, acc[14] * dv, acc[15] * dv);
}

// ---------- CSR aggregation pass 1: 4 lanes/node, float4 gathers, 8-deep MLP, relu epilogue ----------
__global__ __launch_bounds__(256) void k_agg1(const float* __restrict__ hs,
                                              const int* __restrict__ adj,
                                              const int2* __restrict__ rowbe,
                                              const float* __restrict__ dinv,
                                              const float* __restrict__ b1,
                                              float* __restrict__ out, int N) {
    int t = blockIdx.x * 256 + threadIdx.x;
    int n = t >> 2, q = t & 3;
    if (n >= N) return;
    const float4* hs4 = (const float4*)hs;
    int2 be = rowbe[n];
    int beg = be.x, end = be.y;
    float4 a = hs4[(size_t)n * 4 + q];   // self loop (already dinv[src]-scaled)
    float ax = a.x, ay = a.y, az = a.z, aw = a.w;
    int e = beg;
    for (; e + 7 < end; e += 8) {
        int s0 = adj[e], s1 = adj[e + 1], s2 = adj[e + 2], s3 = adj[e + 3];
        int s4 = adj[e + 4], s5 = adj[e + 5], s6 = adj[e + 6], s7 = adj[e + 7];
        float4 v0 = hs4[(size_t)s0 * 4 + q];
        float4 v1 = hs4[(size_t)s1 * 4 + q];
        float4 v2 = hs4[(size_t)s2 * 4 + q];
        float4 v3 = hs4[(size_t)s3 * 4 + q];
        float4 v4 = hs4[(size_t)s4 * 4 + q];
        float4 v5 = hs4[(size_t)s5 * 4 + q];
        float4 v6 = hs4[(size_t)s6 * 4 + q];
        float4 v7 = hs4[(size_t)s7 * 4 + q];
        ax += ((v0.x + v1.x) + (v2.x + v3.x)) + ((v4.x + v5.x) + (v6.x + v7.x));
        ay += ((v0.y + v1.y) + (v2.y + v3.y)) + ((v4.y + v5.y) + (v6.y + v7.y));
        az += ((v0.z + v1.z) + (v2.z + v3.z)) + ((v4.z + v5.z) + (v6.z + v7.z));
        aw += ((v0.w + v1.w) + (v2.w + v3.w)) + ((v4.w + v5.w) + (v6.w + v7.w));
    }
    for (; e + 3 < end; e += 4) {
        int s0 = adj[e], s1 = adj[e + 1], s2 = adj[e + 2], s3 = adj[e + 3];
        float4 v0 = hs4[(size_t)s0 * 4 + q];
        float4 v1 = hs4[(size_t)s1 * 4 + q];
        float4 v2 = hs4[(size_t)s2 * 4 + q];
        float4 v3 = hs4[(size_t)s3 * 4 + q];
        ax += (v0.x + v1.x) + (v2.x + v3.x);
        ay += (v0.y + v1.y) + (v2.y + v3.y);
        az += (v0.z + v1.z) + (v2.z + v3.z);
        aw += (v0.w + v1.w) + (v2.w + v3.w);
    }
    for (; e < end; e++) {
        int s = adj[e];
        float4 v = hs4[(size_t)s * 4 + q];
        ax += v.x; ay += v.y; az += v.z; aw += v.w;
    }
    float dv = dinv[n];
    float4 r;
    r.x = fmaxf(fmaf(dv, ax, b1[q * 4 + 0]), 0.f) * dv;
    r.y = fmaxf(fmaf(dv, ay, b1[q * 4 + 1]), 0.f) * dv;
    r.z = fmaxf(fmaf(dv, az, b1[q * 4 + 2]), 0.f) * dv;
    r.w = fmaxf(fmaf(dv, aw, b1[q * 4 + 3]), 0.f) * dv;
    ((float4*)out)[(size_t)n * 4 + q] = r;
}

// ---------- fused agg pass 2 + W2 + softmax: 4 lanes/node, 64 nodes/block, LDS-staged stores ----------
__global__ __launch_bounds__(256) void k_agg2out(const float* __restrict__ hs,
                                                 const int* __restrict__ adj,
                                                 const int2* __restrict__ rowbe,
                                                 const float* __restrict__ dinv,
                                                 const float* __restrict__ W2,
                                                 const float* __restrict__ b2,
                                                 float* __restrict__ dout, int N) {
    __shared__ float sg[64 * 16];   // 4 KB aggregated layer-2 inputs
    __shared__ float w2s[H * C];    // 2.56 KB
    __shared__ float b2s[C];
    __shared__ float so[64 * 40];   // 10.24 KB output staging (reused for both outputs)
    int t = threadIdx.x;
    for (int i = t; i < H * C; i += 256) w2s[i] = W2[i];
    if (t < C) b2s[t] = b2[t];
    int nl = t >> 2, q = t & 3;
    int n0 = blockIdx.x * 64;
    int n = n0 + nl;
    bool valid = (n < N);
    int nn = valid ? n : N - 1;
    const float4* hs4 = (const float4*)hs;
    int2 be = rowbe[nn];
    int beg = be.x, end = be.y;
    float4 a = hs4[(size_t)nn * 4 + q];  // self loop
    float ax = a.x, ay = a.y, az = a.z, aw = a.w;
    int e = beg;
    for (; e + 7 < end; e += 8) {
        int s0 = adj[e], s1 = adj[e + 1], s2 = adj[e + 2], s3 = adj[e + 3];
        int s4 = adj[e + 4], s5 = adj[e + 5], s6 = adj[e + 6], s7 = adj[e + 7];
        float4 v0 = hs4[(size_t)s0 * 4 + q];
        float4 v1 = hs4[(size_t)s1 * 4 + q];
        float4 v2 = hs4[(size_t)s2 * 4 + q];
        float4 v3 = hs4[(size_t)s3 * 4 + q];
        float4 v4 = hs4[(size_t)s4 * 4 + q];
        float4 v5 = hs4[(size_t)s5 * 4 + q];
        float4 v6 = hs4[(size_t)s6 * 4 + q];
        float4 v7 = hs4[(size_t)s7 * 4 + q];
        ax += ((v0.x + v1.x) + (v2.x + v3.x)) + ((v4.x + v5.x) + (v6.x + v7.x));
        ay += ((v0.y + v1.y) + (v2.y + v3.y)) + ((v4.y + v5.y) + (v6.y + v7.y));
        az += ((v0.z + v1.z) + (v2.z + v3.z)) + ((v4.z + v5.z) + (v6.z + v7.z));
        aw += ((v0.w + v1.w) + (v2.w + v3.w)) + ((v4.w + v5.w) + (v6.w + v7.w));
    }
    for (; e + 3 < end; e += 4) {
        int s0 = adj[e], s1 = adj[e + 1], s2 = adj[e + 2], s3 = adj[e + 3];
        float4 v0 = hs4[(size_t)s0 * 4 + q];
        float4 v1 = hs4[(size_t)s1 * 4 + q];
        float4 v2 = hs4[(size_t)s2 * 4 + q];
        float4 v3 = hs4[(size_t)s3 * 4 + q];
        ax += (v0.x + v1.x) + (v2.x + v3.x);
        ay += (v0.y + v1.y) + (v2.y + v3.y);
        az += (v0.z + v1.z) + (v2.z + v3.z);
        aw += (v0.w + v1.w) + (v2.w + v3.w);
    }
    for (; e < end; e++) {
        int s = adj[e];
        float4 v = hs4[(size_t)s * 4 + q];
        ax += v.x; ay += v.y; az += v.z; aw += v.w;
    }
    float dv = dinv[nn];
    *(float4*)&sg[nl * 16 + q * 4] = make_float4(dv * ax, dv * ay, dv * az, dv * aw);
    __syncthreads();
    // phase 2: lane quad computes 10 of 40 logits for its node
    float g16[16];
    #pragma unroll
    for (int k4 = 0; k4 < 4; k4++) {
        float4 gv = *(const float4*)&sg[nl * 16 + k4 * 4];
        g16[k4 * 4] = gv.x; g16[k4 * 4 + 1] = gv.y;
        g16[k4 * 4 + 2] = gv.z; g16[k4 * 4 + 3] = gv.w;
    }
    int j0 = q * 10;
    float h2[10];
    #pragma unroll
    for (int jj = 0; jj < 10; jj++) {
        float acc = b2s[j0 + jj];
        #pragma unroll
        for (int k = 0; k < H; k++) acc = fmaf(g16[k], w2s[k * C + j0 + jj], acc);
        h2[jj] = acc;
    }
    float m = h2[0];
    #pragma unroll
    for (int jj = 1; jj < 10; jj++) m = fmaxf(m, h2[jj]);
    m = fmaxf(m, __shfl_xor(m, 1, 64));
    m = fmaxf(m, __shfl_xor(m, 2, 64));
    float ex[10], ssum = 0.f;
    #pragma unroll
    for (int jj = 0; jj < 10; jj++) { ex[jj] = __expf(h2[jj] - m); ssum += ex[jj]; }
    ssum += __shfl_xor(ssum, 1, 64);
    ssum += __shfl_xor(ssum, 2, 64);
    float inv = 1.f / ssum;
    // stage softmax rows, coalesced copy out
    int rows = min(64, N - n0);
    int tot = rows * 10;                 // float4 count for this block's rows
    #pragma unroll
    for (int jj = 0; jj < 10; jj++) so[nl * 40 + j0 + jj] = ex[jj] * inv;
    __syncthreads();
    {
        const float4* sp4 = (const float4*)so;
        float4* o4 = (float4*)(dout + (size_t)n0 * C);
        for (int i = t; i < tot; i += 256) o4[i] = sp4[i];
    }
    __syncthreads();
    // stage logits, coalesced copy out
    #pragma unroll
    for (int jj = 0; jj < 10; jj++) so[nl * 40 + j0 + jj] = h2[jj];
    __syncthreads();
    {
        const float4* sp4 = (const float4*)so;
        float4* o4 = (float4*)(dout + (size_t)N * C + (size_t)n0 * C);
        for (int i = t; i < tot; i += 256) o4[i] = sp4[i];
    }
}

extern "C" void kernel_launch(void* const* d_in, const int* in_sizes, int n_in,
                              void* d_out, int out_size, void* d_ws, size_t ws_size,
                              hipStream_t stream) {
    const float* x  = (const float*)d_in[0];
    const int*   ei = (const int*)d_in[1];
    const float* W1 = (const float*)d_in[3];
    const float* b1 = (const float*)d_in[4];
    const float* W2 = (const float*)d_in[5];
    const float* b2 = (const float*)d_in[6];
    float* out = (float*)d_out;

    int N = in_sizes[0] / F;       // 100000
    int E = in_sizes[1] / 2;       // 3200000
    const int* src = ei;
    const int* dst = ei + E;
    int NB  = (N + BW - 1) / BW;            // 782 (<= NB_MAX)
    int NCH = (E + CHUNK - 1) / CHUNK;      // 782

    // workspace layout (keep ebuf 16B-aligned)
    float* ws = (float*)d_ws;
    size_t o = 0;
    int* gcnt  = (int*)(ws + o); o += (size_t)NB_MAX;
    int2* rowbe = (int2*)(ws + o); o += 2 * ((size_t)N + 4);
    o = (o + 3) & ~(size_t)3;
    int* ebuf  = (int*)(ws + o); o += (size_t)NB * SORT_CAP + CHUNK;  // strided buckets + slack
    float* dinv = ws + o;        o += (size_t)N;
    float* h0s  = ws + o;        o += (size_t)N * H;
    float* h1s  = ws + o;        o += (size_t)N * H;

    int ng = (N + 63) / 64;                      // 1563

    hipMemsetAsync(gcnt, 0, (size_t)NB * sizeof(int), stream);
    k_scatfuse<<<NCH, 256, 0, stream>>>(src, dst, gcnt, ebuf, E, NB);
    k_sortb   <<<NB, 256, 0, stream>>>(ebuf, gcnt, rowbe, dinv, N);
    k_gemm1   <<<ng, 64, 0, stream>>>(x, W1, dinv, h0s, N);
    k_agg1    <<<(N * 4 + 255) / 256, 256, 0, stream>>>(h0s, ebuf, rowbe, dinv, b1, h1s, N);
    k_agg2out <<<ng, 256, 0, stream>>>(h1s, ebuf, rowbe, dinv, W2, b2, out, N);
}